// Round 3
// baseline (396.328 us; speedup 1.0000x reference)
//
#include <hip/hip_runtime.h>
#include <hip/hip_bf16.h>
#include <stdint.h>

// Problem dims (fixed): N=4, L=4096, E=1024, H=1024
#define NB 4
#define LS 4096
#define ED 1024
#define HD 1024
#define MR (NB * LS)            // 16384 flattened rows
#define SCALE_S (1.0f / 64.0f)  // 1/sqrt(L)

typedef __attribute__((ext_vector_type(8))) short bf16x8;  // 8 bf16 (4 VGPRs)
typedef __attribute__((ext_vector_type(8))) int   i32x8;   // 32 fp8 bytes (8 VGPRs)
typedef __attribute__((ext_vector_type(4))) float f32x4;

__device__ __forceinline__ unsigned short f2bf(float f) {
    union { float f; uint32_t u; } x; x.f = f;
    uint32_t r = x.u + 0x7fffu + ((x.u >> 16) & 1u);  // RNE
    return (unsigned short)(r >> 16);
}

// async global->LDS, 16B/lane; LDS dest = wave-uniform base + lane*16
__device__ __forceinline__ void load_lds16(const void* g, void* s) {
    __builtin_amdgcn_global_load_lds(
        (const __attribute__((address_space(1))) void*)g,
        (__attribute__((address_space(3))) void*)s, 16, 0, 0);
}

// ---------------- merged cast: X (16384x1024) and Wq|Wk|Wv -> Wall ----------------
#define XCHUNKS (MR * ED / 4)        // 4194304 float4s
#define WCHUNKS (3 * ED * ED / 4)    // 786432 float4s
__global__ void __launch_bounds__(256) cast_all_k(
    const float4* __restrict__ X, const float4* __restrict__ wq,
    const float4* __restrict__ wk, const float4* __restrict__ wv,
    ushort4* __restrict__ Xb, ushort4* __restrict__ Wall)
{
    const int i = blockIdx.x * 256 + threadIdx.x;
    if (i < XCHUNKS) {
        const float4 v = X[i];
        ushort4 o; o.x = f2bf(v.x); o.y = f2bf(v.y); o.z = f2bf(v.z); o.w = f2bf(v.w);
        Xb[i] = o;
    } else if (i < XCHUNKS + WCHUNKS) {
        const int j = i - XCHUNKS;
        const int s = j >> 18, jj = j & 0x3ffff;
        const float4 v = (s == 0 ? wq : s == 1 ? wk : wv)[jj];
        ushort4 o; o.x = f2bf(v.x); o.y = f2bf(v.y); o.z = f2bf(v.z); o.w = f2bf(v.w);
        Wall[j] = o;
    }
}

// ---------------- shared 8-phase schedule macros ----------------
#define QK_BAR() do { asm volatile("" ::: "memory"); \
    __builtin_amdgcn_s_barrier(); asm volatile("" ::: "memory"); } while (0)
#define PH_MID() do { QK_BAR(); \
    asm volatile("s_waitcnt lgkmcnt(0)" ::: "memory"); \
    __builtin_amdgcn_sched_barrier(0); \
    __builtin_amdgcn_s_setprio(1); } while (0)
#define PH_END() do { __builtin_amdgcn_s_setprio(0); QK_BAR(); } while (0)
#define PH_END_VM6() do { __builtin_amdgcn_s_setprio(0); \
    asm volatile("s_waitcnt vmcnt(6)" ::: "memory"); QK_BAR(); } while (0)
#define PH_END_VM0() do { __builtin_amdgcn_s_setprio(0); \
    asm volatile("s_waitcnt vmcnt(0)" ::: "memory"); QK_BAR(); } while (0)

// ---------------- 8-phase fused Q+K projection (256-row x 128-col x {Q,K}) -------
__device__ __forceinline__ void read_af(bf16x8 (&af)[4][2], const char* base,
                                        int arow, int sw7, int quad) {
#pragma unroll
    for (int mf = 0; mf < 4; mf++) {
        const char* r = base + (arow + mf * 16) * 128;
        af[mf][0] = *(const bf16x8*)(r + ((quad * 16) ^ sw7));
        af[mf][1] = *(const bf16x8*)(r + ((64 + quad * 16) ^ sw7));
    }
}
__device__ __forceinline__ void read_wf(bf16x8 (&wf)[4], const char* base,
                                        int wrow, int ks64, int sw7, int quad) {
#pragma unroll
    for (int nf = 0; nf < 4; nf++)
        wf[nf] = *(const bf16x8*)(base + (wrow + nf * 16) * 128 + ((ks64 + quad * 16) ^ sw7));
}
template<int KS>
__device__ __forceinline__ void mfma16(f32x4 (&acc)[4][4], const bf16x8 (&af)[4][2],
                                       const bf16x8 (&wf)[4]) {
#pragma unroll
    for (int mf = 0; mf < 4; mf++)
#pragma unroll
        for (int nf = 0; nf < 4; nf++)
            acc[mf][nf] = __builtin_amdgcn_mfma_f32_16x16x32_bf16(
                wf[nf], af[mf][KS], acc[mf][nf], 0, 0, 0);  // swapped operands
}

// NOTE __launch_bounds__(512, 1): 128 KiB LDS already limits to 1 block/CU.
// Declaring min-waves=2 capped the allocator at 128 VGPR and spilled the
// 128-VGPR accumulator to scratch (R2: WRITE_SIZE 135 MB == 64 spilled
// regs x 512 thr x 1024 blocks). min-waves=1 -> ~256 VGPR budget, no spill.
__global__ void __launch_bounds__(512, 1)
gemm_qk_fused8(const unsigned short* __restrict__ A,   // Xb [16384 x 1024]
               const unsigned short* __restrict__ W,   // Wall [3072 x 1024]
               const float* __restrict__ bq, const float* __restrict__ bk,
               unsigned char* __restrict__ Qf8t, unsigned char* __restrict__ Kf8t,
               float* __restrict__ diag)
{
    extern __shared__ char lds[];  // 128 KiB: buf0 [A 32K | WQ 16K | WK 16K] buf1 [...]
    const int t = threadIdx.x;
    const int w = t >> 6, lane = t & 63, quad = lane >> 4, l16 = lane & 15;
    const int wm = w >> 1, wn = w & 1;

    // XCD-chunked bijective swizzle: 512 blocks, XCD k gets M-panels [8k, 8k+8)
    const int swz = (blockIdx.x & 7) * 64 + (blockIdx.x >> 3);
    const long blockM = (long)(swz >> 3) * 256;
    const int  blockN = (swz & 7) * 128;

    // staging: row r0 = w*8 + (lane>>3); source col-granule pre-swizzled
    const long srow = (long)(w * 8 + (lane >> 3)) * 2048
                    + (long)(((lane & 7) ^ (lane >> 3)) << 4);
    const char* gA  = (const char*)A + blockM * 2048 + srow;
    const char* gAh = gA + 128 * 2048;
    const char* gWq = (const char*)W + (long)blockN * 2048 + srow;
    const char* gWk = gWq + (long)1024 * 2048;
    char* dst = lds + w * 1024;

#define ST(G, OFF, KB) do { \
    load_lds16((G) + (KB), dst + (OFF)); \
    load_lds16((G) + 131072 + (KB), dst + (OFF) + 8192); } while (0)

    const char* A0 = lds;          const char* A1 = lds + 65536;
    const char* Q0 = lds + 32768;  const char* Q1 = lds + 65536 + 32768;
    const char* K0 = lds + 49152;  const char* K1 = lds + 65536 + 49152;

    const int arow = wm * 64 + l16;      // + mf*16
    const int wrow = wn * 64 + l16;      // + nf*16
    const int sw7  = (l16 & 7) << 4;     // row&7 == l16&7 for all frag rows

    f32x4 aq[4][4] = {}; f32x4 ak[4][4] = {};
    bf16x8 aF[4][2], wF[4];

    // prologue: tile0 -> buf0 (4 halves), tile1 -> buf1 (A-lo, A-hi, WQ)
    ST(gA, 0, 0); ST(gAh, 16384, 0); ST(gWq, 32768, 0); ST(gWk, 49152, 0);
    ST(gA, 65536, 128); ST(gAh, 65536 + 16384, 128); ST(gWq, 65536 + 32768, 128);
    asm volatile("s_waitcnt vmcnt(6)" ::: "memory");  // tile0's 8 loads landed
    QK_BAR();

#pragma unroll 1
    for (int i = 0; i < 7; ++i) {
        const long k1 = (2L * i + 1) * 128, k2 = (2L * i + 2) * 128, k3 = (2L * i + 3) * 128;
        // ---- K-tile 2i (buf0) ----
        read_af(aF, A0, arow, sw7, quad);         // 8 reads: ALL A frags (k0+k1)
        read_wf(wF, Q0, wrow, 0, sw7, quad);      // 4 reads: WQ k0
        ST(gWk, 65536 + 49152, k1);               // buf1.WK <- tile 2i+1
        asm volatile("s_waitcnt lgkmcnt(8)" ::: "memory");
        PH_MID(); mfma16<0>(aq, aF, wF); PH_END();
        read_wf(wF, Q0, wrow, 64, sw7, quad);
        ST(gA, 0, k2);                            // buf0.A-lo <- tile 2i+2
        PH_MID(); mfma16<1>(aq, aF, wF); PH_END();
        read_wf(wF, K0, wrow, 0, sw7, quad);
        ST(gAh, 16384, k2);                       // buf0.A-hi
        PH_MID(); mfma16<0>(ak, aF, wF); PH_END();
        read_wf(wF, K0, wrow, 64, sw7, quad);
        ST(gWq, 32768, k2);                       // buf0.WQ
        PH_MID(); mfma16<1>(ak, aF, wF); PH_END_VM6();
        // ---- K-tile 2i+1 (buf1) ----
        read_af(aF, A1, arow, sw7, quad);
        read_wf(wF, Q1, wrow, 0, sw7, quad);
        ST(gWk, 49152, k2);                       // buf0.WK <- tile 2i+2
        asm volatile("s_waitcnt lgkmcnt(8)" ::: "memory");
        PH_MID(); mfma16<0>(aq, aF, wF); PH_END();
        read_wf(wF, Q1, wrow, 64, sw7, quad);
        ST(gA, 65536, k3);                        // buf1.A-lo <- tile 2i+3
        PH_MID(); mfma16<1>(aq, aF, wF); PH_END();
        read_wf(wF, K1, wrow, 0, sw7, quad);
        ST(gAh, 65536 + 16384, k3);               // buf1.A-hi
        PH_MID(); mfma16<0>(ak, aF, wF); PH_END();
        read_wf(wF, K1, wrow, 64, sw7, quad);
        ST(gWq, 65536 + 32768, k3);               // buf1.WQ
        PH_MID(); mfma16<1>(ak, aF, wF); PH_END_VM6();
    }
    // peeled last iteration: tiles 14 (buf0), 15 (buf1); only stage = (15, WK)
    {
        read_af(aF, A0, arow, sw7, quad);
        read_wf(wF, Q0, wrow, 0, sw7, quad);
        ST(gWk, 65536 + 49152, 15L * 128);
        asm volatile("s_waitcnt lgkmcnt(8)" ::: "memory");
        PH_MID(); mfma16<0>(aq, aF, wF); PH_END();
        read_wf(wF, Q0, wrow, 64, sw7, quad);
        PH_MID(); mfma16<1>(aq, aF, wF); PH_END();
        read_wf(wF, K0, wrow, 0, sw7, quad);
        PH_MID(); mfma16<0>(ak, aF, wF); PH_END();
        read_wf(wF, K0, wrow, 64, sw7, quad);
        PH_MID(); mfma16<1>(ak, aF, wF); PH_END_VM0();   // drain: tile15 complete
        read_af(aF, A1, arow, sw7, quad);
        read_wf(wF, Q1, wrow, 0, sw7, quad);
        PH_MID(); mfma16<0>(aq, aF, wF); PH_END();
        read_wf(wF, Q1, wrow, 64, sw7, quad);
        PH_MID(); mfma16<1>(aq, aF, wF); PH_END();
        read_wf(wF, K1, wrow, 0, sw7, quad);
        PH_MID(); mfma16<0>(ak, aF, wF); PH_END();
        read_wf(wF, K1, wrow, 64, sw7, quad);
        PH_MID(); mfma16<1>(ak, aF, wF); PH_END();
    }
#undef ST

    // epilogue: tiled fp8 Q/K + fp32 diag partials
    float dp[4] = {0.f, 0.f, 0.f, 0.f};
#pragma unroll
    for (int nf = 0; nf < 4; nf++) {
        const int col = blockN + wn * 64 + nf * 16 + quad * 4;
        const float4 q4 = *(const float4*)(bq + col);
        const float4 k4 = *(const float4*)(bk + col);
#pragma unroll
        for (int mf = 0; mf < 4; mf++) {
            const size_t row = (size_t)(blockM + wm * 64 + mf * 16 + l16);
            const float vq0 = aq[mf][nf][0] + q4.x, vq1 = aq[mf][nf][1] + q4.y;
            const float vq2 = aq[mf][nf][2] + q4.z, vq3 = aq[mf][nf][3] + q4.w;
            const float vk0 = ak[mf][nf][0] + k4.x, vk1 = ak[mf][nf][1] + k4.y;
            const float vk2 = ak[mf][nf][2] + k4.z, vk3 = ak[mf][nf][3] + k4.w;
            uint32_t uq = 0, uk = 0;
            uq = __builtin_amdgcn_cvt_pk_fp8_f32(vq0, vq1, uq, false);
            uq = __builtin_amdgcn_cvt_pk_fp8_f32(vq2, vq3, uq, true);
            uk = __builtin_amdgcn_cvt_pk_fp8_f32(vk0, vk1, uk, false);
            uk = __builtin_amdgcn_cvt_pk_fp8_f32(vk2, vk3, uk, true);
            const size_t f8 = (row >> 4) * 16384 + (size_t)(col >> 4) * 256
                            + (row & 15) * 16 + (col & 15);
            *(uint32_t*)(Qf8t + f8) = uq;
            *(uint32_t*)(Kf8t + f8) = uk;
            dp[mf] += vq0 * vk0 + vq1 * vk1 + vq2 * vk2 + vq3 * vk3;
        }
    }
#pragma unroll
    for (int mf = 0; mf < 4; mf++) {
        float d = dp[mf];
        d += __shfl_xor(d, 16);
        d += __shfl_xor(d, 32);
        if (quad == 0)
            atomicAdd(&diag[blockM + wm * 64 + mf * 16 + l16], d);
    }
}

// ---------------- V projection (lean): V = Xb * Wv^T + bv -> fp32 d_out ----------------
__global__ void __launch_bounds__(256)
gemm_v(const unsigned short* __restrict__ A,   // Xb
       const unsigned short* __restrict__ Wv,  // Wall + 2*1024*1024
       const float* __restrict__ bv, float* __restrict__ outV)
{
    __shared__ unsigned short As[128 * 32];
    __shared__ unsigned short Bs[128 * 32];

    const int t = threadIdx.x;
    const int wid = t >> 6, lane = t & 63, quad = lane >> 4, l16 = lane & 15;
    const int m0 = (wid >> 1) * 64, n0 = (wid & 1) * 64;
    const long blockM = (long)blockIdx.y * 128;
    const int blockN = blockIdx.x * 128;

    const char* a_g = (const char*)(A  + (blockM + (t >> 2)) * (size_t)ED + (size_t)((t & 3) * 8));
    const char* b_g = (const char*)(Wv + ((size_t)blockN + (t >> 2)) * ED + (size_t)((t & 3) * 8));
    const size_t half = (size_t)64 * ED * 2;

    char* a_s0 = (char*)As + wid * 1024;
    char* b_s0 = (char*)Bs + wid * 1024;

    f32x4 acc[4][4] = {};

    for (int kt = 0; kt < ED; kt += 32) {
        const int kb = kt * 2;
        load_lds16(a_g + kb,        a_s0);
        load_lds16(a_g + kb + half, a_s0 + 4096);
        load_lds16(b_g + kb,        b_s0);
        load_lds16(b_g + kb + half, b_s0 + 4096);
        __syncthreads();

        bf16x8 aF[4], bF[4];
        const char* AsB = (const char*)As;
        const char* BsB = (const char*)Bs;
#pragma unroll
        for (int mf = 0; mf < 4; mf++)
            aF[mf] = *(const bf16x8*)(AsB + ((m0 + mf * 16 + l16) * 32 + quad * 8) * 2);
#pragma unroll
        for (int nf = 0; nf < 4; nf++)
            bF[nf] = *(const bf16x8*)(BsB + ((n0 + nf * 16 + l16) * 32 + quad * 8) * 2);
#pragma unroll
        for (int mf = 0; mf < 4; mf++)
#pragma unroll
            for (int nf = 0; nf < 4; nf++)
                acc[mf][nf] = __builtin_amdgcn_mfma_f32_16x16x32_bf16(
                    bF[nf], aF[mf], acc[mf][nf], 0, 0, 0);  // swapped
        __syncthreads();
    }

#pragma unroll
    for (int mf = 0; mf < 4; mf++) {
        const size_t row = (size_t)(blockM + m0 + mf * 16 + l16);
#pragma unroll
        for (int nf = 0; nf < 4; nf++) {
            const int col = blockN + n0 + nf * 16 + quad * 4;
            const float4 b4 = *(const float4*)(bv + col);
            float4 o;
            o.x = acc[mf][nf][0] + b4.x; o.y = acc[mf][nf][1] + b4.y;
            o.z = acc[mf][nf][2] + b4.z; o.w = acc[mf][nf][3] + b4.w;
            *(float4*)(outV + row * 1024 + col) = o;
        }
    }
}

// ---------------- 8-phase fp8 MX denominator GEMM (256x256, T3+T4+T5) ----------------
__device__ __forceinline__ void read_f8(i32x8 &f, const char* p) {
    const int4 lo = *(const int4*)p;
    const int4 hi = *(const int4*)(p + 256);
    f[0] = lo.x; f[1] = lo.y; f[2] = lo.z; f[3] = lo.w;
    f[4] = hi.x; f[5] = hi.y; f[6] = hi.z; f[7] = hi.w;
}
template<int MF0>
__device__ __forceinline__ void dmfma8(f32x4 (&acc)[8][4], const i32x8 (&aF)[2],
                                       const i32x8 (&bF)[4]) {
#pragma unroll
    for (int j = 0; j < 2; j++)
#pragma unroll
        for (int nf = 0; nf < 4; nf++)
            acc[MF0 + j][nf] = __builtin_amdgcn_mfma_scale_f32_16x16x128_f8f6f4(
                aF[j], bF[nf], acc[MF0 + j][nf],
                0, 0, 0, 0x7f7f7f7f, 0, 0x7f7f7f7f);
}

// __launch_bounds__(512, 1): see note on gemm_qk_fused8 — min-waves=2 forced a
// 128-VGPR cap and spilled the 128-VGPR accumulator (R2 regression).
__global__ void __launch_bounds__(512, 1)
gemm_f8_denom8(const unsigned char* __restrict__ Qt,
               const unsigned char* __restrict__ Kt,
               float* __restrict__ denom)
{
    extern __shared__ char lds[];
    const int t = threadIdx.x;
    const int w = t >> 6, lane = t & 63, quad = lane >> 4, l16 = lane & 15;
    const int wm = w >> 2, wn = w & 3;   // 2M x 4N waves; per-wave 128x64

    // XCD-chunked bijective swizzle over 1024 blocks (1024 % 8 == 0)
    const int pos = (blockIdx.x & 7) * 128 + (blockIdx.x >> 3);
    const int z = pos >> 8;
    const int rem = pos & 255;
    const int blockM = (rem >> 4) * 256;
    const int blockN = (rem & 15) * 256;

    const size_t zoff = (size_t)z * LS * (size_t)HD;
    // stage granule: thread t copies 16B; call j covers row-tiles 4j..4j+3
    const long stg = (long)(t >> 7) * 16384 + (long)(t & 127) * 16;
    const unsigned char* gA = Qt + zoff + (size_t)(blockM >> 4) * 16384 + stg;
    const unsigned char* gB = Kt + zoff + (size_t)(blockN >> 4) * 16384 + stg;

    char* const A0 = lds;
    char* const B0 = lds + 32768;
    char* const A1 = lds + 65536;
    char* const B1 = lds + 98304;

#define STA_(REG, J, KT) load_lds16(gA + (long)(J) * 65536 + (long)(KT) * 2048, \
                                    (REG) + (J) * 8192 + w * 1024)
#define STB_(REG, J, KT) load_lds16(gB + (long)(J) * 65536 + (long)(KT) * 2048, \
                                    (REG) + (J) * 8192 + w * 1024)

    const int abase = (wm * 8) * 2048 + quad * 512 + l16 * 16;
    const int bbase = (wn * 4) * 2048 + quad * 512 + l16 * 16;

    f32x4 acc[8][4] = {};
    i32x8 aF[2], bF[4];

    // prologue: tile0 -> buf0 full; tile1 -> buf1 first-6 (B all, A calls 0,2)
    STA_(A0, 0, 0); STA_(A0, 1, 0); STA_(A0, 2, 0); STA_(A0, 3, 0);
    STB_(B0, 0, 0); STB_(B0, 1, 0); STB_(B0, 2, 0); STB_(B0, 3, 0);
    STB_(B1, 0, 1); STB_(B1, 1, 1); STB_(B1, 2, 1); STB_(B1, 3, 1);
    STA_(A1, 0, 1); STA_(A1, 2, 1);
    asm volatile("s_waitcnt vmcnt(6)" ::: "memory");   // tile0's 8 landed
    QK_BAR();

#pragma unroll 1
    for (int i = 0; i < 3; ++i) {
        const int k1 = 2 * i + 1, k2 = 2 * i + 2, k3 = 2 * i + 3;
        // ---- K-tile 2i (buf0) ----
        read_f8(bF[0], B0 + bbase);        read_f8(bF[1], B0 + bbase + 2048);
        read_f8(bF[2], B0 + bbase + 4096); read_f8(bF[3], B0 + bbase + 6144);
        read_f8(aF[0], A0 + abase);        read_f8(aF[1], A0 + abase + 2048);
        STA_(A1, 1, k1); STA_(A1, 3, k1);            // buf1 last-2 (tile 2i+1)
        asm volatile("s_waitcnt lgkmcnt(8)" ::: "memory");
        PH_MID(); dmfma8<0>(acc, aF, bF); PH_END();
        read_f8(aF[0], A0 + abase + 4096); read_f8(aF[1], A0 + abase + 6144);
        STB_(B0, 0, k2); STB_(B0, 1, k2);            // buf0.B <- tile 2i+2
        PH_MID(); dmfma8<2>(acc, aF, bF); PH_END();
        read_f8(aF[0], A0 + abase + 8192); read_f8(aF[1], A0 + abase + 10240);
        STB_(B0, 2, k2); STB_(B0, 3, k2);
        PH_MID(); dmfma8<4>(acc, aF, bF); PH_END();
        read_f8(aF[0], A0 + abase + 12288); read_f8(aF[1], A0 + abase + 14336);
        STA_(A0, 0, k2); STA_(A0, 2, k2);            // buf0.A calls 0,2
        PH_MID(); dmfma8<6>(acc, aF, bF); PH_END_VM6();
        // ---- K-tile 2i+1 (buf1) ----
        read_f8(bF[0], B1 + bbase);        read_f8(bF[1], B1 + bbase + 2048);
        read_f8(bF[2], B1 + bbase + 4096); read_f8(bF[3], B1 + bbase + 6144);
        read_f8(aF[0], A1 + abase);        read_f8(aF[1], A1 + abase + 2048);
        STA_(A0, 1, k2); STA_(A0, 3, k2);            // buf0 last-2 (tile 2i+2)
        asm volatile("s_waitcnt lgkmcnt(8)" ::: "memory");
        PH_MID(); dmfma8<0>(acc, aF, bF); PH_END();
        read_f8(aF[0], A1 + abase + 4096); read_f8(aF[1], A1 + abase + 6144);
        STB_(B1, 0, k3); STB_(B1, 1, k3);            // buf1.B <- tile 2i+3
        PH_MID(); dmfma8<2>(acc, aF, bF); PH_END();
        read_f8(aF[0], A1 + abase + 8192); read_f8(aF[1], A1 + abase + 10240);
        STB_(B1, 2, k3); STB_(B1, 3, k3);
        PH_MID(); dmfma8<4>(acc, aF, bF); PH_END();
        read_f8(aF[0], A1 + abase + 12288); read_f8(aF[1], A1 + abase + 14336);
        STA_(A1, 0, k3); STA_(A1, 2, k3);            // buf1.A calls 0,2
        PH_MID(); dmfma8<6>(acc, aF, bF); PH_END_VM6();
    }
    // peeled: tile 6 (buf0) stages only buf1 last-2 (tile 7); tile 7 no stages
    {
        read_f8(bF[0], B0 + bbase);        read_f8(bF[1], B0 + bbase + 2048);
        read_f8(bF[2], B0 + bbase + 4096); read_f8(bF[3], B0 + bbase + 6144);
        read_f8(aF[0], A0 + abase);        read_f8(aF[1], A0 + abase + 2048);
        STA_(A1, 1, 7); STA_(A1, 3, 7);
        asm volatile("s_waitcnt lgkmcnt(8)" ::: "memory");
        PH_MID(); dmfma8<0>(acc, aF, bF); PH_END();
        read_f8(aF[0], A0 + abase + 4096); read_f8(aF[1], A0 + abase + 6144);
        PH_MID(); dmfma8<2>(acc, aF, bF); PH_END();
        read_f8(aF[0], A0 + abase + 8192); read_f8(aF[1], A0 + abase + 10240);
        PH_MID(); dmfma8<4>(acc, aF, bF); PH_END();
        read_f8(aF[0], A0 + abase + 12288); read_f8(aF[1], A0 + abase + 14336);
        PH_MID(); dmfma8<6>(acc, aF, bF); PH_END_VM0();  // tile 7 complete
        read_f8(bF[0], B1 + bbase);        read_f8(bF[1], B1 + bbase + 2048);
        read_f8(bF[2], B1 + bbase + 4096); read_f8(bF[3], B1 + bbase + 6144);
        read_f8(aF[0], A1 + abase);        read_f8(aF[1], A1 + abase + 2048);
        PH_MID(); dmfma8<0>(acc, aF, bF); PH_END();
        read_f8(aF[0], A1 + abase + 4096); read_f8(aF[1], A1 + abase + 6144);
        PH_MID(); dmfma8<2>(acc, aF, bF); PH_END();
        read_f8(aF[0], A1 + abase + 8192); read_f8(aF[1], A1 + abase + 10240);
        PH_MID(); dmfma8<4>(acc, aF, bF); PH_END();
        read_f8(aF[0], A1 + abase + 12288); read_f8(aF[1], A1 + abase + 14336);
        PH_MID(); dmfma8<6>(acc, aF, bF);
        __builtin_amdgcn_s_setprio(0);
    }
#undef STA_
#undef STB_

    // epilogue: denom[b] = sum_a exp(S[a][b]/64); C/D col = l16, rows = quad*4+r
    float* dn = denom + (size_t)z * LS;
#pragma unroll
    for (int nf = 0; nf < 4; nf++) {
        float s = 0.f;
#pragma unroll
        for (int mf = 0; mf < 8; mf++)
#pragma unroll
            for (int r = 0; r < 4; r++)
                s += __expf(acc[mf][nf][r] * SCALE_S);
        s += __shfl_xor(s, 16);
        s += __shfl_xor(s, 32);
        if (quad == 0)
            atomicAdd(&dn[blockN + wn * 64 + nf * 16 + l16], s);
    }
}

// ---------------- finalize: out[row,:] *= exp(diag[row]/64)/denom[row] ----------------
__global__ void __launch_bounds__(256) finalize_k(
    float* __restrict__ out, const float* __restrict__ diag,
    const float* __restrict__ denom)
{
    const int row = blockIdx.x;
    const float sc = __expf(diag[row] * SCALE_S) / denom[row];
    float4* p = (float4*)(out + (size_t)row * HD) + threadIdx.x;
    float4 v = *p;
    v.x *= sc; v.y *= sc; v.z *= sc; v.w *= sc;
    *p = v;
}

extern "C" void kernel_launch(void* const* d_in, const int* in_sizes, int n_in,
                              void* d_out, int out_size, void* d_ws, size_t ws_size,
                              hipStream_t stream)
{
    (void)in_sizes; (void)n_in; (void)out_size; (void)ws_size;
    const float* X  = (const float*)d_in[0];
    const float* Wq = (const float*)d_in[1];
    const float* bq = (const float*)d_in[2];
    const float* Wk = (const float*)d_in[3];
    const float* bk = (const float*)d_in[4];
    const float* Wv = (const float*)d_in[5];
    const float* bv = (const float*)d_in[6];
    float* out = (float*)d_out;

    // workspace layout (~73.5 MB)
    char* p = (char*)d_ws;
    unsigned short* Xb   = (unsigned short*)p; p += (size_t)MR * ED * 2;   // 33.55 MB
    unsigned short* Wall = (unsigned short*)p; p += (size_t)3072 * ED * 2; //  6.29 MB
    unsigned char*  Qf8t = (unsigned char*)p;  p += (size_t)MR * HD;       // 16.78 MB (tiled)
    unsigned char*  Kf8t = (unsigned char*)p;  p += (size_t)MR * HD;       // 16.78 MB (tiled)
    float* diag  = (float*)p; p += (size_t)MR * 4;                         // adjacent:
    float* denom = (float*)p; p += (size_t)MR * 4;                         // one memset

    dim3 blk(256);

    // one-time: allow 128 KiB dynamic LDS on the 8-phase kernels
    static int init8 = 0;
    if (!init8) {
        hipFuncSetAttribute((const void*)gemm_qk_fused8,
                            hipFuncAttributeMaxDynamicSharedMemorySize, 131072);
        hipFuncSetAttribute((const void*)gemm_f8_denom8,
                            hipFuncAttributeMaxDynamicSharedMemorySize, 131072);
        init8 = 1;
    }

    // 1) merged casts (X -> bf16, Wq|Wk|Wv -> Wall bf16)
    cast_all_k<<<(XCHUNKS + WCHUNKS + 255) / 256, blk, 0, stream>>>(
        (const float4*)X, (const float4*)Wq, (const float4*)Wk, (const float4*)Wv,
        (ushort4*)Xb, (ushort4*)Wall);

    // 2) zero diag+denom (atomic accumulators)
    hipMemsetAsync(diag, 0, 2 * MR * sizeof(float), stream);

    // 3) fused Q+K projection, 8-phase 256x(128x2) -> tiled fp8 + fp32 diag partials
    gemm_qk_fused8<<<dim3(512), dim3(512), 131072, stream>>>(
        Xb, Wall, bq, bk, Qf8t, Kf8t, diag);

    // 4) V projection -> fp32 directly into d_out
    dim3 gv(HD / 128, MR / 128);
    gemm_v<<<gv, blk, 0, stream>>>(Xb, Wall + (size_t)2048 * ED, bv, out);

    // 5) column denominators via 8-phase MX-fp8 GEMM (256x256)
    gemm_f8_denom8<<<dim3(1024), dim3(512), 131072, stream>>>(Qf8t, Kf8t, denom);

    // 6) out *= exp(diag/64)/denom (in place on V)
    finalize_k<<<MR, blk, 0, stream>>>(out, diag, denom);
}

// Round 4
// 388.924 us; speedup vs baseline: 1.0190x; 1.0190x over previous
//
#include <hip/hip_runtime.h>
#include <hip/hip_bf16.h>
#include <stdint.h>

// Problem dims (fixed): N=4, L=4096, E=1024, H=1024
#define NB 4
#define LS 4096
#define ED 1024
#define HD 1024
#define MR (NB * LS)            // 16384 flattened rows
#define SCALE_S (1.0f / 64.0f)  // 1/sqrt(L)

typedef __attribute__((ext_vector_type(8))) short bf16x8;  // 8 bf16 (4 VGPRs)
typedef __attribute__((ext_vector_type(8))) int   i32x8;   // 32 fp8 bytes (8 VGPRs)
typedef __attribute__((ext_vector_type(4))) float f32x4;

__device__ __forceinline__ unsigned short f2bf(float f) {
    union { float f; uint32_t u; } x; x.f = f;
    uint32_t r = x.u + 0x7fffu + ((x.u >> 16) & 1u);  // RNE
    return (unsigned short)(r >> 16);
}

// async global->LDS, 16B/lane; LDS dest = wave-uniform base + lane*16
__device__ __forceinline__ void load_lds16(const void* g, void* s) {
    __builtin_amdgcn_global_load_lds(
        (const __attribute__((address_space(1))) void*)g,
        (__attribute__((address_space(3))) void*)s, 16, 0, 0);
}

// ---------------- merged cast: X (16384x1024) and Wq|Wk|Wv -> Wall ----------------
#define XCHUNKS (MR * ED / 4)        // 4194304 float4s
#define WCHUNKS (3 * ED * ED / 4)    // 786432 float4s
__global__ void __launch_bounds__(256) cast_all_k(
    const float4* __restrict__ X, const float4* __restrict__ wq,
    const float4* __restrict__ wk, const float4* __restrict__ wv,
    ushort4* __restrict__ Xb, ushort4* __restrict__ Wall)
{
    const int i = blockIdx.x * 256 + threadIdx.x;
    if (i < XCHUNKS) {
        const float4 v = X[i];
        ushort4 o; o.x = f2bf(v.x); o.y = f2bf(v.y); o.z = f2bf(v.z); o.w = f2bf(v.w);
        Xb[i] = o;
    } else if (i < XCHUNKS + WCHUNKS) {
        const int j = i - XCHUNKS;
        const int s = j >> 18, jj = j & 0x3ffff;
        const float4 v = (s == 0 ? wq : s == 1 ? wk : wv)[jj];
        ushort4 o; o.x = f2bf(v.x); o.y = f2bf(v.y); o.z = f2bf(v.z); o.w = f2bf(v.w);
        Wall[j] = o;
    }
}

// ---------------- shared 8-phase schedule macros ----------------
#define QK_BAR() do { asm volatile("" ::: "memory"); \
    __builtin_amdgcn_s_barrier(); asm volatile("" ::: "memory"); } while (0)
#define PH_MID() do { QK_BAR(); \
    asm volatile("s_waitcnt lgkmcnt(0)" ::: "memory"); \
    __builtin_amdgcn_sched_barrier(0); \
    __builtin_amdgcn_s_setprio(1); } while (0)
#define PH_END() do { __builtin_amdgcn_s_setprio(0); QK_BAR(); } while (0)
#define PH_END_VM6() do { __builtin_amdgcn_s_setprio(0); \
    asm volatile("s_waitcnt vmcnt(6)" ::: "memory"); QK_BAR(); } while (0)
#define PH_END_VM0() do { __builtin_amdgcn_s_setprio(0); \
    asm volatile("s_waitcnt vmcnt(0)" ::: "memory"); QK_BAR(); } while (0)

// ---------------- 8-phase fused Q+K projection (256-row x 128-col x {Q,K}) -------
__device__ __forceinline__ void read_af(bf16x8 (&af)[4][2], const char* base,
                                        int arow, int sw7, int quad) {
#pragma unroll
    for (int mf = 0; mf < 4; mf++) {
        const char* r = base + (arow + mf * 16) * 128;
        af[mf][0] = *(const bf16x8*)(r + ((quad * 16) ^ sw7));
        af[mf][1] = *(const bf16x8*)(r + ((64 + quad * 16) ^ sw7));
    }
}
__device__ __forceinline__ void read_wf(bf16x8 (&wf)[4], const char* base,
                                        int wrow, int ks64, int sw7, int quad) {
#pragma unroll
    for (int nf = 0; nf < 4; nf++)
        wf[nf] = *(const bf16x8*)(base + (wrow + nf * 16) * 128 + ((ks64 + quad * 16) ^ sw7));
}
template<int KS>
__device__ __forceinline__ void mfma16(f32x4 (&acc)[4][4], const bf16x8 (&af)[4][2],
                                       const bf16x8 (&wf)[4]) {
#pragma unroll
    for (int mf = 0; mf < 4; mf++)
#pragma unroll
        for (int nf = 0; nf < 4; nf++)
            acc[mf][nf] = __builtin_amdgcn_mfma_f32_16x16x32_bf16(
                wf[nf], af[mf][KS], acc[mf][nf], 0, 0, 0);  // swapped operands
}

// REGISTER-BUDGET NOTE (R2/R3 post-mortem): with dynamic LDS the backend's
// occupancy calculator sees 0 B LDS and targets 4 waves/EU -> 128-reg unified
// budget -> ~64 regs/thread spilled to scratch (R2/R3: WRITE_SIZE 132 MiB,
// identical for launch_bounds min-waves 1 and 2 — the min is only a floor).
// amdgpu_waves_per_eu(2,2) sets the MAX, clamping the target to the 2
// waves/EU that 128 KiB LDS permits anyway -> 256-reg budget, no spill.
__global__ void __launch_bounds__(512) __attribute__((amdgpu_waves_per_eu(2, 2)))
gemm_qk_fused8(const unsigned short* __restrict__ A,   // Xb [16384 x 1024]
               const unsigned short* __restrict__ W,   // Wall [3072 x 1024]
               const float* __restrict__ bq, const float* __restrict__ bk,
               unsigned char* __restrict__ Qf8t, unsigned char* __restrict__ Kf8t,
               float* __restrict__ diag)
{
    extern __shared__ char lds[];  // 128 KiB: buf0 [A 32K | WQ 16K | WK 16K] buf1 [...]
    const int t = threadIdx.x;
    const int w = t >> 6, lane = t & 63, quad = lane >> 4, l16 = lane & 15;
    const int wm = w >> 1, wn = w & 1;

    // XCD-chunked bijective swizzle: 512 blocks, XCD k gets M-panels [8k, 8k+8)
    const int swz = (blockIdx.x & 7) * 64 + (blockIdx.x >> 3);
    const long blockM = (long)(swz >> 3) * 256;
    const int  blockN = (swz & 7) * 128;

    // staging: row r0 = w*8 + (lane>>3); source col-granule pre-swizzled
    const long srow = (long)(w * 8 + (lane >> 3)) * 2048
                    + (long)(((lane & 7) ^ (lane >> 3)) << 4);
    const char* gA  = (const char*)A + blockM * 2048 + srow;
    const char* gAh = gA + 128 * 2048;
    const char* gWq = (const char*)W + (long)blockN * 2048 + srow;
    const char* gWk = gWq + (long)1024 * 2048;
    char* dst = lds + w * 1024;

#define ST(G, OFF, KB) do { \
    load_lds16((G) + (KB), dst + (OFF)); \
    load_lds16((G) + 131072 + (KB), dst + (OFF) + 8192); } while (0)

    const char* A0 = lds;          const char* A1 = lds + 65536;
    const char* Q0 = lds + 32768;  const char* Q1 = lds + 65536 + 32768;
    const char* K0 = lds + 49152;  const char* K1 = lds + 65536 + 49152;

    const int arow = wm * 64 + l16;      // + mf*16
    const int wrow = wn * 64 + l16;      // + nf*16
    const int sw7  = (l16 & 7) << 4;     // row&7 == l16&7 for all frag rows

    f32x4 aq[4][4] = {}; f32x4 ak[4][4] = {};
    bf16x8 aF[4][2], wF[4];

    // prologue: tile0 -> buf0 (4 halves), tile1 -> buf1 (A-lo, A-hi, WQ)
    ST(gA, 0, 0); ST(gAh, 16384, 0); ST(gWq, 32768, 0); ST(gWk, 49152, 0);
    ST(gA, 65536, 128); ST(gAh, 65536 + 16384, 128); ST(gWq, 65536 + 32768, 128);
    asm volatile("s_waitcnt vmcnt(6)" ::: "memory");  // tile0's 8 loads landed
    QK_BAR();

#pragma unroll 1
    for (int i = 0; i < 7; ++i) {
        const long k1 = (2L * i + 1) * 128, k2 = (2L * i + 2) * 128, k3 = (2L * i + 3) * 128;
        // ---- K-tile 2i (buf0) ----
        read_af(aF, A0, arow, sw7, quad);         // 8 reads: ALL A frags (k0+k1)
        read_wf(wF, Q0, wrow, 0, sw7, quad);      // 4 reads: WQ k0
        ST(gWk, 65536 + 49152, k1);               // buf1.WK <- tile 2i+1
        asm volatile("s_waitcnt lgkmcnt(8)" ::: "memory");
        PH_MID(); mfma16<0>(aq, aF, wF); PH_END();
        read_wf(wF, Q0, wrow, 64, sw7, quad);
        ST(gA, 0, k2);                            // buf0.A-lo <- tile 2i+2
        PH_MID(); mfma16<1>(aq, aF, wF); PH_END();
        read_wf(wF, K0, wrow, 0, sw7, quad);
        ST(gAh, 16384, k2);                       // buf0.A-hi
        PH_MID(); mfma16<0>(ak, aF, wF); PH_END();
        read_wf(wF, K0, wrow, 64, sw7, quad);
        ST(gWq, 32768, k2);                       // buf0.WQ
        PH_MID(); mfma16<1>(ak, aF, wF); PH_END_VM6();
        // ---- K-tile 2i+1 (buf1) ----
        read_af(aF, A1, arow, sw7, quad);
        read_wf(wF, Q1, wrow, 0, sw7, quad);
        ST(gWk, 49152, k2);                       // buf0.WK <- tile 2i+2
        asm volatile("s_waitcnt lgkmcnt(8)" ::: "memory");
        PH_MID(); mfma16<0>(aq, aF, wF); PH_END();
        read_wf(wF, Q1, wrow, 64, sw7, quad);
        ST(gA, 65536, k3);                        // buf1.A-lo <- tile 2i+3
        PH_MID(); mfma16<1>(aq, aF, wF); PH_END();
        read_wf(wF, K1, wrow, 0, sw7, quad);
        ST(gAh, 65536 + 16384, k3);               // buf1.A-hi
        PH_MID(); mfma16<0>(ak, aF, wF); PH_END();
        read_wf(wF, K1, wrow, 64, sw7, quad);
        ST(gWq, 65536 + 32768, k3);               // buf1.WQ
        PH_MID(); mfma16<1>(ak, aF, wF); PH_END_VM6();
    }
    // peeled last iteration: tiles 14 (buf0), 15 (buf1); only stage = (15, WK)
    {
        read_af(aF, A0, arow, sw7, quad);
        read_wf(wF, Q0, wrow, 0, sw7, quad);
        ST(gWk, 65536 + 49152, 15L * 128);
        asm volatile("s_waitcnt lgkmcnt(8)" ::: "memory");
        PH_MID(); mfma16<0>(aq, aF, wF); PH_END();
        read_wf(wF, Q0, wrow, 64, sw7, quad);
        PH_MID(); mfma16<1>(aq, aF, wF); PH_END();
        read_wf(wF, K0, wrow, 0, sw7, quad);
        PH_MID(); mfma16<0>(ak, aF, wF); PH_END();
        read_wf(wF, K0, wrow, 64, sw7, quad);
        PH_MID(); mfma16<1>(ak, aF, wF); PH_END_VM0();   // drain: tile15 complete
        read_af(aF, A1, arow, sw7, quad);
        read_wf(wF, Q1, wrow, 0, sw7, quad);
        PH_MID(); mfma16<0>(aq, aF, wF); PH_END();
        read_wf(wF, Q1, wrow, 64, sw7, quad);
        PH_MID(); mfma16<1>(aq, aF, wF); PH_END();
        read_wf(wF, K1, wrow, 0, sw7, quad);
        PH_MID(); mfma16<0>(ak, aF, wF); PH_END();
        read_wf(wF, K1, wrow, 64, sw7, quad);
        PH_MID(); mfma16<1>(ak, aF, wF); PH_END();
    }
#undef ST

    // epilogue: tiled fp8 Q/K + fp32 diag partials
    float dp[4] = {0.f, 0.f, 0.f, 0.f};
#pragma unroll
    for (int nf = 0; nf < 4; nf++) {
        const int col = blockN + wn * 64 + nf * 16 + quad * 4;
        const float4 q4 = *(const float4*)(bq + col);
        const float4 k4 = *(const float4*)(bk + col);
#pragma unroll
        for (int mf = 0; mf < 4; mf++) {
            const size_t row = (size_t)(blockM + wm * 64 + mf * 16 + l16);
            const float vq0 = aq[mf][nf][0] + q4.x, vq1 = aq[mf][nf][1] + q4.y;
            const float vq2 = aq[mf][nf][2] + q4.z, vq3 = aq[mf][nf][3] + q4.w;
            const float vk0 = ak[mf][nf][0] + k4.x, vk1 = ak[mf][nf][1] + k4.y;
            const float vk2 = ak[mf][nf][2] + k4.z, vk3 = ak[mf][nf][3] + k4.w;
            uint32_t uq = 0, uk = 0;
            uq = __builtin_amdgcn_cvt_pk_fp8_f32(vq0, vq1, uq, false);
            uq = __builtin_amdgcn_cvt_pk_fp8_f32(vq2, vq3, uq, true);
            uk = __builtin_amdgcn_cvt_pk_fp8_f32(vk0, vk1, uk, false);
            uk = __builtin_amdgcn_cvt_pk_fp8_f32(vk2, vk3, uk, true);
            const size_t f8 = (row >> 4) * 16384 + (size_t)(col >> 4) * 256
                            + (row & 15) * 16 + (col & 15);
            *(uint32_t*)(Qf8t + f8) = uq;
            *(uint32_t*)(Kf8t + f8) = uk;
            dp[mf] += vq0 * vk0 + vq1 * vk1 + vq2 * vk2 + vq3 * vk3;
        }
    }
#pragma unroll
    for (int mf = 0; mf < 4; mf++) {
        float d = dp[mf];
        d += __shfl_xor(d, 16);
        d += __shfl_xor(d, 32);
        if (quad == 0)
            atomicAdd(&diag[blockM + wm * 64 + mf * 16 + l16], d);
    }
}

// ---------------- V projection (lean): V = Xb * Wv^T + bv -> fp32 d_out ----------------
__global__ void __launch_bounds__(256)
gemm_v(const unsigned short* __restrict__ A,   // Xb
       const unsigned short* __restrict__ Wv,  // Wall + 2*1024*1024
       const float* __restrict__ bv, float* __restrict__ outV)
{
    __shared__ unsigned short As[128 * 32];
    __shared__ unsigned short Bs[128 * 32];

    const int t = threadIdx.x;
    const int wid = t >> 6, lane = t & 63, quad = lane >> 4, l16 = lane & 15;
    const int m0 = (wid >> 1) * 64, n0 = (wid & 1) * 64;
    const long blockM = (long)blockIdx.y * 128;
    const int blockN = blockIdx.x * 128;

    const char* a_g = (const char*)(A  + (blockM + (t >> 2)) * (size_t)ED + (size_t)((t & 3) * 8));
    const char* b_g = (const char*)(Wv + ((size_t)blockN + (t >> 2)) * ED + (size_t)((t & 3) * 8));
    const size_t half = (size_t)64 * ED * 2;

    char* a_s0 = (char*)As + wid * 1024;
    char* b_s0 = (char*)Bs + wid * 1024;

    f32x4 acc[4][4] = {};

    for (int kt = 0; kt < ED; kt += 32) {
        const int kb = kt * 2;
        load_lds16(a_g + kb,        a_s0);
        load_lds16(a_g + kb + half, a_s0 + 4096);
        load_lds16(b_g + kb,        b_s0);
        load_lds16(b_g + kb + half, b_s0 + 4096);
        __syncthreads();

        bf16x8 aF[4], bF[4];
        const char* AsB = (const char*)As;
        const char* BsB = (const char*)Bs;
#pragma unroll
        for (int mf = 0; mf < 4; mf++)
            aF[mf] = *(const bf16x8*)(AsB + ((m0 + mf * 16 + l16) * 32 + quad * 8) * 2);
#pragma unroll
        for (int nf = 0; nf < 4; nf++)
            bF[nf] = *(const bf16x8*)(BsB + ((n0 + nf * 16 + l16) * 32 + quad * 8) * 2);
#pragma unroll
        for (int mf = 0; mf < 4; mf++)
#pragma unroll
            for (int nf = 0; nf < 4; nf++)
                acc[mf][nf] = __builtin_amdgcn_mfma_f32_16x16x32_bf16(
                    bF[nf], aF[mf], acc[mf][nf], 0, 0, 0);  // swapped
        __syncthreads();
    }

#pragma unroll
    for (int mf = 0; mf < 4; mf++) {
        const size_t row = (size_t)(blockM + m0 + mf * 16 + l16);
#pragma unroll
        for (int nf = 0; nf < 4; nf++) {
            const int col = blockN + n0 + nf * 16 + quad * 4;
            const float4 b4 = *(const float4*)(bv + col);
            float4 o;
            o.x = acc[mf][nf][0] + b4.x; o.y = acc[mf][nf][1] + b4.y;
            o.z = acc[mf][nf][2] + b4.z; o.w = acc[mf][nf][3] + b4.w;
            *(float4*)(outV + row * 1024 + col) = o;
        }
    }
}

// ---------------- 8-phase fp8 MX denominator GEMM (256x256, T3+T4+T5) ----------------
__device__ __forceinline__ void read_f8(i32x8 &f, const char* p) {
    const int4 lo = *(const int4*)p;
    const int4 hi = *(const int4*)(p + 256);
    f[0] = lo.x; f[1] = lo.y; f[2] = lo.z; f[3] = lo.w;
    f[4] = hi.x; f[5] = hi.y; f[6] = hi.z; f[7] = hi.w;
}
template<int MF0>
__device__ __forceinline__ void dmfma8(f32x4 (&acc)[8][4], const i32x8 (&aF)[2],
                                       const i32x8 (&bF)[4]) {
#pragma unroll
    for (int j = 0; j < 2; j++)
#pragma unroll
        for (int nf = 0; nf < 4; nf++)
            acc[MF0 + j][nf] = __builtin_amdgcn_mfma_scale_f32_16x16x128_f8f6f4(
                aF[j], bF[nf], acc[MF0 + j][nf],
                0, 0, 0, 0x7f7f7f7f, 0, 0x7f7f7f7f);
}

// amdgpu_waves_per_eu(2,2): see note on gemm_qk_fused8 (R2/R3 spill fix).
__global__ void __launch_bounds__(512) __attribute__((amdgpu_waves_per_eu(2, 2)))
gemm_f8_denom8(const unsigned char* __restrict__ Qt,
               const unsigned char* __restrict__ Kt,
               float* __restrict__ denom)
{
    extern __shared__ char lds[];
    const int t = threadIdx.x;
    const int w = t >> 6, lane = t & 63, quad = lane >> 4, l16 = lane & 15;
    const int wm = w >> 2, wn = w & 3;   // 2M x 4N waves; per-wave 128x64

    // XCD-chunked bijective swizzle over 1024 blocks (1024 % 8 == 0)
    const int pos = (blockIdx.x & 7) * 128 + (blockIdx.x >> 3);
    const int z = pos >> 8;
    const int rem = pos & 255;
    const int blockM = (rem >> 4) * 256;
    const int blockN = (rem & 15) * 256;

    const size_t zoff = (size_t)z * LS * (size_t)HD;
    // stage granule: thread t copies 16B; call j covers row-tiles 4j..4j+3
    const long stg = (long)(t >> 7) * 16384 + (long)(t & 127) * 16;
    const unsigned char* gA = Qt + zoff + (size_t)(blockM >> 4) * 16384 + stg;
    const unsigned char* gB = Kt + zoff + (size_t)(blockN >> 4) * 16384 + stg;

    char* const A0 = lds;
    char* const B0 = lds + 32768;
    char* const A1 = lds + 65536;
    char* const B1 = lds + 98304;

#define STA_(REG, J, KT) load_lds16(gA + (long)(J) * 65536 + (long)(KT) * 2048, \
                                    (REG) + (J) * 8192 + w * 1024)
#define STB_(REG, J, KT) load_lds16(gB + (long)(J) * 65536 + (long)(KT) * 2048, \
                                    (REG) + (J) * 8192 + w * 1024)

    const int abase = (wm * 8) * 2048 + quad * 512 + l16 * 16;
    const int bbase = (wn * 4) * 2048 + quad * 512 + l16 * 16;

    f32x4 acc[8][4] = {};
    i32x8 aF[2], bF[4];

    // prologue: tile0 -> buf0 full; tile1 -> buf1 first-6 (B all, A calls 0,2)
    STA_(A0, 0, 0); STA_(A0, 1, 0); STA_(A0, 2, 0); STA_(A0, 3, 0);
    STB_(B0, 0, 0); STB_(B0, 1, 0); STB_(B0, 2, 0); STB_(B0, 3, 0);
    STB_(B1, 0, 1); STB_(B1, 1, 1); STB_(B1, 2, 1); STB_(B1, 3, 1);
    STA_(A1, 0, 1); STA_(A1, 2, 1);
    asm volatile("s_waitcnt vmcnt(6)" ::: "memory");   // tile0's 8 landed
    QK_BAR();

#pragma unroll 1
    for (int i = 0; i < 3; ++i) {
        const int k1 = 2 * i + 1, k2 = 2 * i + 2, k3 = 2 * i + 3;
        // ---- K-tile 2i (buf0) ----
        read_f8(bF[0], B0 + bbase);        read_f8(bF[1], B0 + bbase + 2048);
        read_f8(bF[2], B0 + bbase + 4096); read_f8(bF[3], B0 + bbase + 6144);
        read_f8(aF[0], A0 + abase);        read_f8(aF[1], A0 + abase + 2048);
        STA_(A1, 1, k1); STA_(A1, 3, k1);            // buf1 last-2 (tile 2i+1)
        asm volatile("s_waitcnt lgkmcnt(8)" ::: "memory");
        PH_MID(); dmfma8<0>(acc, aF, bF); PH_END();
        read_f8(aF[0], A0 + abase + 4096); read_f8(aF[1], A0 + abase + 6144);
        STB_(B0, 0, k2); STB_(B0, 1, k2);            // buf0.B <- tile 2i+2
        PH_MID(); dmfma8<2>(acc, aF, bF); PH_END();
        read_f8(aF[0], A0 + abase + 8192); read_f8(aF[1], A0 + abase + 10240);
        STB_(B0, 2, k2); STB_(B0, 3, k2);
        PH_MID(); dmfma8<4>(acc, aF, bF); PH_END();
        read_f8(aF[0], A0 + abase + 12288); read_f8(aF[1], A0 + abase + 14336);
        STA_(A0, 0, k2); STA_(A0, 2, k2);            // buf0.A calls 0,2
        PH_MID(); dmfma8<6>(acc, aF, bF); PH_END_VM6();
        // ---- K-tile 2i+1 (buf1) ----
        read_f8(bF[0], B1 + bbase);        read_f8(bF[1], B1 + bbase + 2048);
        read_f8(bF[2], B1 + bbase + 4096); read_f8(bF[3], B1 + bbase + 6144);
        read_f8(aF[0], A1 + abase);        read_f8(aF[1], A1 + abase + 2048);
        STA_(A0, 1, k2); STA_(A0, 3, k2);            // buf0 last-2 (tile 2i+2)
        asm volatile("s_waitcnt lgkmcnt(8)" ::: "memory");
        PH_MID(); dmfma8<0>(acc, aF, bF); PH_END();
        read_f8(aF[0], A1 + abase + 4096); read_f8(aF[1], A1 + abase + 6144);
        STB_(B1, 0, k3); STB_(B1, 1, k3);            // buf1.B <- tile 2i+3
        PH_MID(); dmfma8<2>(acc, aF, bF); PH_END();
        read_f8(aF[0], A1 + abase + 8192); read_f8(aF[1], A1 + abase + 10240);
        STB_(B1, 2, k3); STB_(B1, 3, k3);
        PH_MID(); dmfma8<4>(acc, aF, bF); PH_END();
        read_f8(aF[0], A1 + abase + 12288); read_f8(aF[1], A1 + abase + 14336);
        STA_(A1, 0, k3); STA_(A1, 2, k3);            // buf1.A calls 0,2
        PH_MID(); dmfma8<6>(acc, aF, bF); PH_END_VM6();
    }
    // peeled: tile 6 (buf0) stages only buf1 last-2 (tile 7); tile 7 no stages
    {
        read_f8(bF[0], B0 + bbase);        read_f8(bF[1], B0 + bbase + 2048);
        read_f8(bF[2], B0 + bbase + 4096); read_f8(bF[3], B0 + bbase + 6144);
        read_f8(aF[0], A0 + abase);        read_f8(aF[1], A0 + abase + 2048);
        STA_(A1, 1, 7); STA_(A1, 3, 7);
        asm volatile("s_waitcnt lgkmcnt(8)" ::: "memory");
        PH_MID(); dmfma8<0>(acc, aF, bF); PH_END();
        read_f8(aF[0], A0 + abase + 4096); read_f8(aF[1], A0 + abase + 6144);
        PH_MID(); dmfma8<2>(acc, aF, bF); PH_END();
        read_f8(aF[0], A0 + abase + 8192); read_f8(aF[1], A0 + abase + 10240);
        PH_MID(); dmfma8<4>(acc, aF, bF); PH_END();
        read_f8(aF[0], A0 + abase + 12288); read_f8(aF[1], A0 + abase + 14336);
        PH_MID(); dmfma8<6>(acc, aF, bF); PH_END_VM0();  // tile 7 complete
        read_f8(bF[0], B1 + bbase);        read_f8(bF[1], B1 + bbase + 2048);
        read_f8(bF[2], B1 + bbase + 4096); read_f8(bF[3], B1 + bbase + 6144);
        read_f8(aF[0], A1 + abase);        read_f8(aF[1], A1 + abase + 2048);
        PH_MID(); dmfma8<0>(acc, aF, bF); PH_END();
        read_f8(aF[0], A1 + abase + 4096); read_f8(aF[1], A1 + abase + 6144);
        PH_MID(); dmfma8<2>(acc, aF, bF); PH_END();
        read_f8(aF[0], A1 + abase + 8192); read_f8(aF[1], A1 + abase + 10240);
        PH_MID(); dmfma8<4>(acc, aF, bF); PH_END();
        read_f8(aF[0], A1 + abase + 12288); read_f8(aF[1], A1 + abase + 14336);
        PH_MID(); dmfma8<6>(acc, aF, bF);
        __builtin_amdgcn_s_setprio(0);
    }
#undef STA_
#undef STB_

    // epilogue: denom[b] = sum_a exp(S[a][b]/64); C/D col = l16, rows = quad*4+r
    float* dn = denom + (size_t)z * LS;
#pragma unroll
    for (int nf = 0; nf < 4; nf++) {
        float s = 0.f;
#pragma unroll
        for (int mf = 0; mf < 8; mf++)
#pragma unroll
            for (int r = 0; r < 4; r++)
                s += __expf(acc[mf][nf][r] * SCALE_S);
        s += __shfl_xor(s, 16);
        s += __shfl_xor(s, 32);
        if (quad == 0)
            atomicAdd(&dn[blockN + wn * 64 + nf * 16 + l16], s);
    }
}

// ---------------- finalize: out[row,:] *= exp(diag[row]/64)/denom[row] ----------------
__global__ void __launch_bounds__(256) finalize_k(
    float* __restrict__ out, const float* __restrict__ diag,
    const float* __restrict__ denom)
{
    const int row = blockIdx.x;
    const float sc = __expf(diag[row] * SCALE_S) / denom[row];
    float4* p = (float4*)(out + (size_t)row * HD) + threadIdx.x;
    float4 v = *p;
    v.x *= sc; v.y *= sc; v.z *= sc; v.w *= sc;
    *p = v;
}

extern "C" void kernel_launch(void* const* d_in, const int* in_sizes, int n_in,
                              void* d_out, int out_size, void* d_ws, size_t ws_size,
                              hipStream_t stream)
{
    (void)in_sizes; (void)n_in; (void)out_size; (void)ws_size;
    const float* X  = (const float*)d_in[0];
    const float* Wq = (const float*)d_in[1];
    const float* bq = (const float*)d_in[2];
    const float* Wk = (const float*)d_in[3];
    const float* bk = (const float*)d_in[4];
    const float* Wv = (const float*)d_in[5];
    const float* bv = (const float*)d_in[6];
    float* out = (float*)d_out;

    // workspace layout (~73.5 MB)
    char* p = (char*)d_ws;
    unsigned short* Xb   = (unsigned short*)p; p += (size_t)MR * ED * 2;   // 33.55 MB
    unsigned short* Wall = (unsigned short*)p; p += (size_t)3072 * ED * 2; //  6.29 MB
    unsigned char*  Qf8t = (unsigned char*)p;  p += (size_t)MR * HD;       // 16.78 MB (tiled)
    unsigned char*  Kf8t = (unsigned char*)p;  p += (size_t)MR * HD;       // 16.78 MB (tiled)
    float* diag  = (float*)p; p += (size_t)MR * 4;                         // adjacent:
    float* denom = (float*)p; p += (size_t)MR * 4;                         // one memset

    dim3 blk(256);

    // one-time: allow 128 KiB dynamic LDS on the 8-phase kernels
    static int init8 = 0;
    if (!init8) {
        hipFuncSetAttribute((const void*)gemm_qk_fused8,
                            hipFuncAttributeMaxDynamicSharedMemorySize, 131072);
        hipFuncSetAttribute((const void*)gemm_f8_denom8,
                            hipFuncAttributeMaxDynamicSharedMemorySize, 131072);
        init8 = 1;
    }

    // 1) merged casts (X -> bf16, Wq|Wk|Wv -> Wall bf16)
    cast_all_k<<<(XCHUNKS + WCHUNKS + 255) / 256, blk, 0, stream>>>(
        (const float4*)X, (const float4*)Wq, (const float4*)Wk, (const float4*)Wv,
        (ushort4*)Xb, (ushort4*)Wall);

    // 2) zero diag+denom (atomic accumulators)
    hipMemsetAsync(diag, 0, 2 * MR * sizeof(float), stream);

    // 3) fused Q+K projection, 8-phase 256x(128x2) -> tiled fp8 + fp32 diag partials
    gemm_qk_fused8<<<dim3(512), dim3(512), 131072, stream>>>(
        Xb, Wall, bq, bk, Qf8t, Kf8t, diag);

    // 4) V projection -> fp32 directly into d_out
    dim3 gv(HD / 128, MR / 128);
    gemm_v<<<gv, blk, 0, stream>>>(Xb, Wall + (size_t)2048 * ED, bv, out);

    // 5) column denominators via 8-phase MX-fp8 GEMM (256x256)
    gemm_f8_denom8<<<dim3(1024), dim3(512), 131072, stream>>>(Qf8t, Kf8t, denom);

    // 6) out *= exp(diag/64)/denom (in place on V)
    finalize_k<<<MR, blk, 0, stream>>>(out, diag, denom);
}

// Round 5
// 307.138 us; speedup vs baseline: 1.2904x; 1.2663x over previous
//
#include <hip/hip_runtime.h>
#include <hip/hip_bf16.h>
#include <stdint.h>

// Problem dims (fixed): N=4, L=4096, E=1024, H=1024
#define NB 4
#define LS 4096
#define ED 1024
#define HD 1024
#define MR (NB * LS)            // 16384 flattened rows
#define SCALE_S (1.0f / 64.0f)  // 1/sqrt(L)

typedef __attribute__((ext_vector_type(8))) short bf16x8;  // 8 bf16 (4 VGPRs)
typedef __attribute__((ext_vector_type(8))) int   i32x8;   // 32 fp8 bytes (8 VGPRs)
typedef __attribute__((ext_vector_type(4))) float f32x4;

__device__ __forceinline__ unsigned short f2bf(float f) {
    union { float f; uint32_t u; } x; x.f = f;
    uint32_t r = x.u + 0x7fffu + ((x.u >> 16) & 1u);  // RNE
    return (unsigned short)(r >> 16);
}

// async global->LDS, 16B/lane; LDS dest = wave-uniform base + lane*16
__device__ __forceinline__ void load_lds16(const void* g, void* s) {
    __builtin_amdgcn_global_load_lds(
        (const __attribute__((address_space(1))) void*)g,
        (__attribute__((address_space(3))) void*)s, 16, 0, 0);
}

// ---------------- merged cast: X (16384x1024) and Wq|Wk|Wv -> Wall ----------------
#define XCHUNKS (MR * ED / 4)        // 4194304 float4s
#define WCHUNKS (3 * ED * ED / 4)    // 786432 float4s
__global__ void __launch_bounds__(256) cast_all_k(
    const float4* __restrict__ X, const float4* __restrict__ wq,
    const float4* __restrict__ wk, const float4* __restrict__ wv,
    ushort4* __restrict__ Xb, ushort4* __restrict__ Wall)
{
    const int i = blockIdx.x * 256 + threadIdx.x;
    if (i < XCHUNKS) {
        const float4 v = X[i];
        ushort4 o; o.x = f2bf(v.x); o.y = f2bf(v.y); o.z = f2bf(v.z); o.w = f2bf(v.w);
        Xb[i] = o;
    } else if (i < XCHUNKS + WCHUNKS) {
        const int j = i - XCHUNKS;
        const int s = j >> 18, jj = j & 0x3ffff;
        const float4 v = (s == 0 ? wq : s == 1 ? wk : wv)[jj];
        ushort4 o; o.x = f2bf(v.x); o.y = f2bf(v.y); o.z = f2bf(v.z); o.w = f2bf(v.w);
        Wall[j] = o;
    }
}

// ---------------- shared schedule macros ----------------
#define QK_BAR() do { asm volatile("" ::: "memory"); \
    __builtin_amdgcn_s_barrier(); asm volatile("" ::: "memory"); } while (0)
#define PH_MID() do { QK_BAR(); \
    asm volatile("s_waitcnt lgkmcnt(0)" ::: "memory"); \
    __builtin_amdgcn_sched_barrier(0); \
    __builtin_amdgcn_s_setprio(1); } while (0)
#define PH_END() do { __builtin_amdgcn_s_setprio(0); QK_BAR(); } while (0)
#define PH_END_VM6() do { __builtin_amdgcn_s_setprio(0); \
    asm volatile("s_waitcnt vmcnt(6)" ::: "memory"); QK_BAR(); } while (0)
#define PH_END_VM0() do { __builtin_amdgcn_s_setprio(0); \
    asm volatile("s_waitcnt vmcnt(0)" ::: "memory"); QK_BAR(); } while (0)

// ---------------- 8-phase fused Q+K projection (256-row x 128-col x {Q,K}) -------
__device__ __forceinline__ void read_af(bf16x8 (&af)[4][2], const char* base,
                                        int arow, int sw7, int quad) {
#pragma unroll
    for (int mf = 0; mf < 4; mf++) {
        const char* r = base + (arow + mf * 16) * 128;
        af[mf][0] = *(const bf16x8*)(r + ((quad * 16) ^ sw7));
        af[mf][1] = *(const bf16x8*)(r + ((64 + quad * 16) ^ sw7));
    }
}
__device__ __forceinline__ void read_wf(bf16x8 (&wf)[4], const char* base,
                                        int wrow, int ks64, int sw7, int quad) {
#pragma unroll
    for (int nf = 0; nf < 4; nf++)
        wf[nf] = *(const bf16x8*)(base + (wrow + nf * 16) * 128 + ((ks64 + quad * 16) ^ sw7));
}
template<int KS>
__device__ __forceinline__ void mfma16(f32x4 (&acc)[4][4], const bf16x8 (&af)[4][2],
                                       const bf16x8 (&wf)[4]) {
#pragma unroll
    for (int mf = 0; mf < 4; mf++)
#pragma unroll
        for (int nf = 0; nf < 4; nf++)
            acc[mf][nf] = __builtin_amdgcn_mfma_f32_16x16x32_bf16(
                wf[nf], af[mf][KS], acc[mf][nf], 0, 0, 0);  // swapped operands
}

__global__ void __launch_bounds__(512) __attribute__((amdgpu_waves_per_eu(2, 2)))
gemm_qk_fused8(const unsigned short* __restrict__ A,   // Xb [16384 x 1024]
               const unsigned short* __restrict__ W,   // Wall [3072 x 1024]
               const float* __restrict__ bq, const float* __restrict__ bk,
               unsigned char* __restrict__ Qf8t, unsigned char* __restrict__ Kf8t,
               float* __restrict__ diag)
{
    extern __shared__ char lds[];  // 128 KiB: buf0 [A 32K | WQ 16K | WK 16K] buf1 [...]
    const int t = threadIdx.x;
    const int w = t >> 6, lane = t & 63, quad = lane >> 4, l16 = lane & 15;
    const int wm = w >> 1, wn = w & 1;

    // XCD-chunked bijective swizzle: 512 blocks, XCD k gets M-panels [8k, 8k+8)
    const int swz = (blockIdx.x & 7) * 64 + (blockIdx.x >> 3);
    const long blockM = (long)(swz >> 3) * 256;
    const int  blockN = (swz & 7) * 128;

    // staging: row r0 = w*8 + (lane>>3); source col-granule pre-swizzled
    const long srow = (long)(w * 8 + (lane >> 3)) * 2048
                    + (long)(((lane & 7) ^ (lane >> 3)) << 4);
    const char* gA  = (const char*)A + blockM * 2048 + srow;
    const char* gAh = gA + 128 * 2048;
    const char* gWq = (const char*)W + (long)blockN * 2048 + srow;
    const char* gWk = gWq + (long)1024 * 2048;
    char* dst = lds + w * 1024;

#define ST(G, OFF, KB) do { \
    load_lds16((G) + (KB), dst + (OFF)); \
    load_lds16((G) + 131072 + (KB), dst + (OFF) + 8192); } while (0)

    const char* A0 = lds;          const char* A1 = lds + 65536;
    const char* Q0 = lds + 32768;  const char* Q1 = lds + 65536 + 32768;
    const char* K0 = lds + 49152;  const char* K1 = lds + 65536 + 49152;

    const int arow = wm * 64 + l16;      // + mf*16
    const int wrow = wn * 64 + l16;      // + nf*16
    const int sw7  = (l16 & 7) << 4;     // row&7 == l16&7 for all frag rows

    f32x4 aq[4][4] = {}; f32x4 ak[4][4] = {};
    bf16x8 aF[4][2], wF[4];

    // prologue: tile0 -> buf0 (4 halves), tile1 -> buf1 (A-lo, A-hi, WQ)
    ST(gA, 0, 0); ST(gAh, 16384, 0); ST(gWq, 32768, 0); ST(gWk, 49152, 0);
    ST(gA, 65536, 128); ST(gAh, 65536 + 16384, 128); ST(gWq, 65536 + 32768, 128);
    asm volatile("s_waitcnt vmcnt(6)" ::: "memory");  // tile0's 8 loads landed
    QK_BAR();

#pragma unroll 1
    for (int i = 0; i < 7; ++i) {
        const long k1 = (2L * i + 1) * 128, k2 = (2L * i + 2) * 128, k3 = (2L * i + 3) * 128;
        // ---- K-tile 2i (buf0) ----
        read_af(aF, A0, arow, sw7, quad);         // 8 reads: ALL A frags (k0+k1)
        read_wf(wF, Q0, wrow, 0, sw7, quad);      // 4 reads: WQ k0
        ST(gWk, 65536 + 49152, k1);               // buf1.WK <- tile 2i+1
        asm volatile("s_waitcnt lgkmcnt(8)" ::: "memory");
        PH_MID(); mfma16<0>(aq, aF, wF); PH_END();
        read_wf(wF, Q0, wrow, 64, sw7, quad);
        ST(gA, 0, k2);                            // buf0.A-lo <- tile 2i+2
        PH_MID(); mfma16<1>(aq, aF, wF); PH_END();
        read_wf(wF, K0, wrow, 0, sw7, quad);
        ST(gAh, 16384, k2);                       // buf0.A-hi
        PH_MID(); mfma16<0>(ak, aF, wF); PH_END();
        read_wf(wF, K0, wrow, 64, sw7, quad);
        ST(gWq, 32768, k2);                       // buf0.WQ
        PH_MID(); mfma16<1>(ak, aF, wF); PH_END_VM6();
        // ---- K-tile 2i+1 (buf1) ----
        read_af(aF, A1, arow, sw7, quad);
        read_wf(wF, Q1, wrow, 0, sw7, quad);
        ST(gWk, 49152, k2);                       // buf0.WK <- tile 2i+2
        asm volatile("s_waitcnt lgkmcnt(8)" ::: "memory");
        PH_MID(); mfma16<0>(aq, aF, wF); PH_END();
        read_wf(wF, Q1, wrow, 64, sw7, quad);
        ST(gA, 65536, k3);                        // buf1.A-lo <- tile 2i+3
        PH_MID(); mfma16<1>(aq, aF, wF); PH_END();
        read_wf(wF, K1, wrow, 0, sw7, quad);
        ST(gAh, 65536 + 16384, k3);               // buf1.A-hi
        PH_MID(); mfma16<0>(ak, aF, wF); PH_END();
        read_wf(wF, K1, wrow, 64, sw7, quad);
        ST(gWq, 65536 + 32768, k3);               // buf1.WQ
        PH_MID(); mfma16<1>(ak, aF, wF); PH_END_VM6();
    }
    // peeled last iteration: tiles 14 (buf0), 15 (buf1); only stage = (15, WK)
    {
        read_af(aF, A0, arow, sw7, quad);
        read_wf(wF, Q0, wrow, 0, sw7, quad);
        ST(gWk, 65536 + 49152, 15L * 128);
        asm volatile("s_waitcnt lgkmcnt(8)" ::: "memory");
        PH_MID(); mfma16<0>(aq, aF, wF); PH_END();
        read_wf(wF, Q0, wrow, 64, sw7, quad);
        PH_MID(); mfma16<1>(aq, aF, wF); PH_END();
        read_wf(wF, K0, wrow, 0, sw7, quad);
        PH_MID(); mfma16<0>(ak, aF, wF); PH_END();
        read_wf(wF, K0, wrow, 64, sw7, quad);
        PH_MID(); mfma16<1>(ak, aF, wF); PH_END_VM0();   // drain: tile15 complete
        read_af(aF, A1, arow, sw7, quad);
        read_wf(wF, Q1, wrow, 0, sw7, quad);
        PH_MID(); mfma16<0>(aq, aF, wF); PH_END();
        read_wf(wF, Q1, wrow, 64, sw7, quad);
        PH_MID(); mfma16<1>(aq, aF, wF); PH_END();
        read_wf(wF, K1, wrow, 0, sw7, quad);
        PH_MID(); mfma16<0>(ak, aF, wF); PH_END();
        read_wf(wF, K1, wrow, 64, sw7, quad);
        PH_MID(); mfma16<1>(ak, aF, wF); PH_END();
    }
#undef ST

    // epilogue: tiled fp8 Q/K + fp32 diag partials
    float dp[4] = {0.f, 0.f, 0.f, 0.f};
#pragma unroll
    for (int nf = 0; nf < 4; nf++) {
        const int col = blockN + wn * 64 + nf * 16 + quad * 4;
        const float4 q4 = *(const float4*)(bq + col);
        const float4 k4 = *(const float4*)(bk + col);
#pragma unroll
        for (int mf = 0; mf < 4; mf++) {
            const size_t row = (size_t)(blockM + wm * 64 + mf * 16 + l16);
            const float vq0 = aq[mf][nf][0] + q4.x, vq1 = aq[mf][nf][1] + q4.y;
            const float vq2 = aq[mf][nf][2] + q4.z, vq3 = aq[mf][nf][3] + q4.w;
            const float vk0 = ak[mf][nf][0] + k4.x, vk1 = ak[mf][nf][1] + k4.y;
            const float vk2 = ak[mf][nf][2] + k4.z, vk3 = ak[mf][nf][3] + k4.w;
            uint32_t uq = 0, uk = 0;
            uq = __builtin_amdgcn_cvt_pk_fp8_f32(vq0, vq1, uq, false);
            uq = __builtin_amdgcn_cvt_pk_fp8_f32(vq2, vq3, uq, true);
            uk = __builtin_amdgcn_cvt_pk_fp8_f32(vk0, vk1, uk, false);
            uk = __builtin_amdgcn_cvt_pk_fp8_f32(vk2, vk3, uk, true);
            const size_t f8 = (row >> 4) * 16384 + (size_t)(col >> 4) * 256
                            + (row & 15) * 16 + (col & 15);
            *(uint32_t*)(Qf8t + f8) = uq;
            *(uint32_t*)(Kf8t + f8) = uk;
            dp[mf] += vq0 * vk0 + vq1 * vk1 + vq2 * vk2 + vq3 * vk3;
        }
    }
#pragma unroll
    for (int mf = 0; mf < 4; mf++) {
        float d = dp[mf];
        d += __shfl_xor(d, 16);
        d += __shfl_xor(d, 32);
        if (quad == 0)
            atomicAdd(&diag[blockM + wm * 64 + mf * 16 + l16], d);
    }
}

// ---------------- fp8 MX denominator GEMM (R0-proven 2-phase 128x128) ----------------
__global__ void __launch_bounds__(256)
gemm_f8_denom(const unsigned char* __restrict__ Qt,
              const unsigned char* __restrict__ Kt,
              float* __restrict__ denom)
{
    __shared__ __align__(16) unsigned char As[16384];
    __shared__ __align__(16) unsigned char Bs[16384];

    const int t = threadIdx.x;
    const int wid = t >> 6, lane = t & 63, quad = lane >> 4, l16 = lane & 15;
    const int m0 = (wid >> 1) * 64, n0 = (wid & 1) * 64;
    const size_t zoff = (size_t)blockIdx.z * LS * (size_t)HD;
    const unsigned char* A = Qt + zoff;
    const unsigned char* B = Kt + zoff;
    float* dn = denom + (size_t)blockIdx.z * LS;
    const int blockM = blockIdx.y * 128;
    const int blockN = blockIdx.x * 128;

    size_t aoff[4], boff[4];
#pragma unroll
    for (int j = 0; j < 4; j++) {
        const int iw = wid * 4 + j;
        const size_t lo = (size_t)((iw & 1) * 4 + (lane >> 4)) * 256 + (size_t)(lane & 15) * 16;
        aoff[j] = ((size_t)(blockM >> 4) + (iw >> 1)) * 16384 + lo;
        boff[j] = ((size_t)(blockN >> 4) + (iw >> 1)) * 16384 + lo;
    }

    f32x4 acc[4][4] = {};

    for (int kt = 0; kt < 8; kt++) {           // 8 k-tiles of 128 bytes
        const size_t ko = (size_t)kt * 2048;
#pragma unroll
        for (int j = 0; j < 4; j++) {
            load_lds16(A + aoff[j] + ko, (char*)As + (wid * 4 + j) * 1024);
            load_lds16(B + boff[j] + ko, (char*)Bs + (wid * 4 + j) * 1024);
        }
        __syncthreads();

        i32x8 aF[4], bF[4];
#pragma unroll
        for (int mf = 0; mf < 4; mf++) {
            const int base = (((m0 >> 4) + mf) * 2048) + quad * 512 + l16 * 16;
            const int4 lo = *(const int4*)(As + base);
            const int4 hi = *(const int4*)(As + base + 256);
            aF[mf][0] = lo.x; aF[mf][1] = lo.y; aF[mf][2] = lo.z; aF[mf][3] = lo.w;
            aF[mf][4] = hi.x; aF[mf][5] = hi.y; aF[mf][6] = hi.z; aF[mf][7] = hi.w;
        }
#pragma unroll
        for (int nf = 0; nf < 4; nf++) {
            const int base = (((n0 >> 4) + nf) * 2048) + quad * 512 + l16 * 16;
            const int4 lo = *(const int4*)(Bs + base);
            const int4 hi = *(const int4*)(Bs + base + 256);
            bF[nf][0] = lo.x; bF[nf][1] = lo.y; bF[nf][2] = lo.z; bF[nf][3] = lo.w;
            bF[nf][4] = hi.x; bF[nf][5] = hi.y; bF[nf][6] = hi.z; bF[nf][7] = hi.w;
        }
#pragma unroll
        for (int mf = 0; mf < 4; mf++)
#pragma unroll
            for (int nf = 0; nf < 4; nf++)
                acc[mf][nf] = __builtin_amdgcn_mfma_scale_f32_16x16x128_f8f6f4(
                    aF[mf], bF[nf], acc[mf][nf],
                    0, 0,              // cbsz=FP8, blgp=FP8
                    0, 0x7f7f7f7f,     // scale_a = 1.0 (E8M0 127)
                    0, 0x7f7f7f7f);    // scale_b = 1.0
        __syncthreads();
    }

    // C/D: col = lane&15 (K-row -> output col), rows = quad*4+reg
#pragma unroll
    for (int nf = 0; nf < 4; nf++) {
        float s = 0.f;
#pragma unroll
        for (int mf = 0; mf < 4; mf++)
#pragma unroll
            for (int r = 0; r < 4; r++)
                s += __expf(acc[mf][nf][r] * SCALE_S);
        s += __shfl_xor(s, 16);
        s += __shfl_xor(s, 32);
        if (quad == 0)
            atomicAdd(&dn[blockN + n0 + nf * 16 + l16], s);
    }
}

// ---------------- V projection + fused finalize (register-budgeted pipeline) ----------
// out[row,col] = (Xb[row,:] . Wv[col,:] + bv[col]) * exp(diag[row]/64)/denom[row]
// 256x128 tile, 8 waves (4M x 2N -> per-wave 64x64, acc = 64 f32). BK=32 so
// frags are bf16x8 (aF[4]+wF[4] = 32 VGPR). Designed to fit the 128-VGPR cap
// observed in R2-R4 (dyn-LDS 512-thr kernels): ~115 live regs -> NO spill.
// 3 LDS buffers x 24KB (72 KiB): tile t stages tile t+2 into the buffer freed
// at t-1. One barrier per K-tile; counted vmcnt(3) (never 0 in loop) = T4.
// Bank fix: 64B rows are a 4-way b128 conflict; involution swizzle
// slot ^= (row&3) applied on global source granule AND ds_read (rule 21).
__global__ void __launch_bounds__(512)
gemm_v8fin(const unsigned short* __restrict__ A,   // Xb
           const unsigned short* __restrict__ Wv,  // Wall + 2*1024*1024
           const float* __restrict__ bv, const float* __restrict__ diag,
           const float* __restrict__ denom, float* __restrict__ out)
{
    extern __shared__ char lds[];  // 3 bufs x [A 16K | W 8K]
    const int t = threadIdx.x;
    const int w = t >> 6, lane = t & 63, quad = lane >> 4, l16 = lane & 15;
    const int wm = w >> 1, wn = w & 1;

    // same XCD-chunked swizzle as QK8 (512 blocks)
    const int swz = (blockIdx.x & 7) * 64 + (blockIdx.x >> 3);
    const long blockM = (long)(swz >> 3) * 256;
    const int  blockN = (swz & 7) * 128;

    // staging: thread t covers row t>>2 (of a 128-row half), 16B granule,
    // source col-slot pre-swizzled by (row&3)
    const int scol = (((t & 3) ^ ((t >> 2) & 3)) << 4);
    const char* gA0 = (const char*)A + (blockM + (t >> 2)) * 2048 + scol;
    const char* gA1 = gA0 + 128 * 2048;
    const char* gW0 = (const char*)Wv + ((long)blockN + (t >> 2)) * 2048 + scol;

    const int arow = wm * 64 + l16;                  // + mf*16
    const int wrow = wn * 64 + l16;                  // + nf*16
    const int rdoff = (quad * 16) ^ ((l16 & 3) << 4);  // swizzled read slot

    f32x4 acc[4][4] = {};
    bf16x8 aF[4], wF[4];

#define VBA(J) (lds + (J) * 24576)
#define VST(J, KT) do { \
    load_lds16(gA0 + (long)(KT) * 64, VBA(J) + w * 1024); \
    load_lds16(gA1 + (long)(KT) * 64, VBA(J) + 8192 + w * 1024); \
    load_lds16(gW0 + (long)(KT) * 64, VBA(J) + 16384 + w * 1024); } while (0)
#define VREAD(J) do { \
    const char* Ab_ = VBA(J); const char* Wb_ = VBA(J) + 16384; \
    _Pragma("unroll") for (int mf = 0; mf < 4; mf++) \
        aF[mf] = *(const bf16x8*)(Ab_ + (arow + mf * 16) * 64 + rdoff); \
    _Pragma("unroll") for (int nf = 0; nf < 4; nf++) \
        wF[nf] = *(const bf16x8*)(Wb_ + (wrow + nf * 16) * 64 + rdoff); } while (0)
#define VCOMP() do { \
    asm volatile("s_waitcnt lgkmcnt(0)" ::: "memory"); \
    __builtin_amdgcn_sched_barrier(0); \
    __builtin_amdgcn_s_setprio(1); \
    _Pragma("unroll") for (int mf = 0; mf < 4; mf++) \
    _Pragma("unroll") for (int nf = 0; nf < 4; nf++) \
        acc[mf][nf] = __builtin_amdgcn_mfma_f32_16x16x32_bf16( \
            wF[nf], aF[mf], acc[mf][nf], 0, 0, 0); \
    __builtin_amdgcn_s_setprio(0); } while (0)
#define VEND3() do { asm volatile("s_waitcnt vmcnt(3)" ::: "memory"); QK_BAR(); } while (0)

    // prologue: tiles 0,1 -> bufs 0,1
    VST(0, 0); VST(1, 1);
    asm volatile("s_waitcnt vmcnt(3)" ::: "memory");  // tile0's 3 landed
    QK_BAR();

#pragma unroll 1
    for (int i = 0; i < 10; ++i) {
        const int b = 3 * i;
        VREAD(0); VST(2, b + 2); VCOMP(); VEND3();   // tile 3i
        VREAD(1); VST(0, b + 3); VCOMP(); VEND3();   // tile 3i+1
        VREAD(2); VST(1, b + 4); VCOMP(); VEND3();   // tile 3i+2
    }
    // peeled: tile 30 (buf0, no stage) then tile 31 (buf1)
    VREAD(0); VCOMP();
    asm volatile("s_waitcnt vmcnt(0)" ::: "memory"); QK_BAR();
    VREAD(1); VCOMP();
#undef VBA
#undef VST
#undef VREAD
#undef VCOMP
#undef VEND3

    // epilogue: bias + fused finalize scale, write final output
#pragma unroll
    for (int mf = 0; mf < 4; mf++) {
        const long row = blockM + wm * 64 + mf * 16 + l16;
        const float sc = __expf(diag[row] * SCALE_S) / denom[row];
#pragma unroll
        for (int nf = 0; nf < 4; nf++) {
            const int col = blockN + wn * 64 + nf * 16 + quad * 4;
            const float4 b4 = *(const float4*)(bv + col);
            float4 o;
            o.x = (acc[mf][nf][0] + b4.x) * sc;
            o.y = (acc[mf][nf][1] + b4.y) * sc;
            o.z = (acc[mf][nf][2] + b4.z) * sc;
            o.w = (acc[mf][nf][3] + b4.w) * sc;
            *(float4*)(out + row * 1024 + col) = o;
        }
    }
}

extern "C" void kernel_launch(void* const* d_in, const int* in_sizes, int n_in,
                              void* d_out, int out_size, void* d_ws, size_t ws_size,
                              hipStream_t stream)
{
    (void)in_sizes; (void)n_in; (void)out_size; (void)ws_size;
    const float* X  = (const float*)d_in[0];
    const float* Wq = (const float*)d_in[1];
    const float* bq = (const float*)d_in[2];
    const float* Wk = (const float*)d_in[3];
    const float* bk = (const float*)d_in[4];
    const float* Wv = (const float*)d_in[5];
    const float* bv = (const float*)d_in[6];
    float* out = (float*)d_out;

    // workspace layout (~73.5 MB)
    char* p = (char*)d_ws;
    unsigned short* Xb   = (unsigned short*)p; p += (size_t)MR * ED * 2;   // 33.55 MB
    unsigned short* Wall = (unsigned short*)p; p += (size_t)3072 * ED * 2; //  6.29 MB
    unsigned char*  Qf8t = (unsigned char*)p;  p += (size_t)MR * HD;       // 16.78 MB (tiled)
    unsigned char*  Kf8t = (unsigned char*)p;  p += (size_t)MR * HD;       // 16.78 MB (tiled)
    float* diag  = (float*)p; p += (size_t)MR * 4;                         // adjacent:
    float* denom = (float*)p; p += (size_t)MR * 4;                         // one memset

    dim3 blk(256);

    // one-time: allow dynamic LDS beyond default
    static int init8 = 0;
    if (!init8) {
        hipFuncSetAttribute((const void*)gemm_qk_fused8,
                            hipFuncAttributeMaxDynamicSharedMemorySize, 131072);
        hipFuncSetAttribute((const void*)gemm_v8fin,
                            hipFuncAttributeMaxDynamicSharedMemorySize, 73728);
        init8 = 1;
    }

    // 1) merged casts (X -> bf16, Wq|Wk|Wv -> Wall bf16)
    cast_all_k<<<(XCHUNKS + WCHUNKS + 255) / 256, blk, 0, stream>>>(
        (const float4*)X, (const float4*)Wq, (const float4*)Wk, (const float4*)Wv,
        (ushort4*)Xb, (ushort4*)Wall);

    // 2) zero diag+denom (atomic accumulators)
    hipMemsetAsync(diag, 0, 2 * MR * sizeof(float), stream);

    // 3) fused Q+K projection, 8-phase 256x(128x2) -> tiled fp8 + fp32 diag partials
    gemm_qk_fused8<<<dim3(512), dim3(512), 131072, stream>>>(
        Xb, Wall, bq, bk, Qf8t, Kf8t, diag);

    // 4) column denominators via 2-phase MX-fp8 GEMM (128x128, R0-proven)
    dim3 gden(LS / 128, LS / 128, NB);
    gemm_f8_denom<<<gden, blk, 0, stream>>>(Qf8t, Kf8t, denom);

    // 5) V projection + fused finalize -> final output (replaces gemm_v + finalize_k)
    gemm_v8fin<<<dim3(512), dim3(512), 73728, stream>>>(
        Xb, Wall + (size_t)2048 * ED, bv, diag, denom, out);
}